// Round 1
// baseline (95.739 us; speedup 1.0000x reference)
//
#include <hip/hip_runtime.h>
#include <math.h>

// Shapes (fixed by the reference):
//   x: (64,196,768) f32, ln_w/ln_b: (768,), sw/sb: (196,2,196), dw: (196,2)
// Algebra:
//   W[o,n]   = dw[o,0]*sw[o,0,n] + dw[o,1]*sw[o,1,n]
//   c[o]     = dw[o,0]*sum_n sb[o,0,n] + dw[o,1]*sum_n sb[o,1,n]
//   rowsum[o]= sum_n W[o,n]
//   xh[b,n,d]= (x[b,n,d]-mu[b,n])*rstd[b,n]
//   t[b,o,d] = ln_w[d]*sum_n W[o,n]*xh[b,n,d] + ln_b[d]*rowsum[o] + c[o]
//   out[b,o,d] = x[b,o,d] * (gelu_erf(t) + 1)

#define B_   64
#define N_   196   // n == o == 196
#define D_   768
#define KPAD 208   // 13*16, zero-padded K for the GEMM
#define OPAD 256   // 4*64, zero-padded M

// ws layout (floats):
//   Wt[KPAD][OPAD]  : transposed, zero-padded W   (53248)
//   rowsum[OPAD]    :                              (256)
//   c[OPAD]         :                              (256)
//   mu[B_*N_]       :                              (12544)
//   rstd[B_*N_]     :                              (12544)

__global__ void prep_w_kernel(const float* __restrict__ sw,
                              const float* __restrict__ sb,
                              const float* __restrict__ dw,
                              float* __restrict__ Wt,
                              float* __restrict__ rowsum,
                              float* __restrict__ cvec) {
    int o = blockIdx.x;   // 0..255 (>=196 are zero pad rows)
    int t = threadIdx.x;  // 0..255
    float w0 = 0.f, w1 = 0.f;
    if (o < N_) { w0 = dw[o * 2 + 0]; w1 = dw[o * 2 + 1]; }
    float val = 0.f, sbp = 0.f;
    if (o < N_ && t < N_) {
        val = w0 * sw[(o * 2 + 0) * N_ + t] + w1 * sw[(o * 2 + 1) * N_ + t];
        sbp = w0 * sb[(o * 2 + 0) * N_ + t] + w1 * sb[(o * 2 + 1) * N_ + t];
    }
    if (t < KPAD) Wt[t * OPAD + o] = val;  // transposed store, pad rows get 0
    __shared__ float r1[256], r2[256];
    r1[t] = val; r2[t] = sbp;
    __syncthreads();
    for (int s = 128; s > 0; s >>= 1) {
        if (t < s) { r1[t] += r1[t + s]; r2[t] += r2[t + s]; }
        __syncthreads();
    }
    if (t == 0) { rowsum[o] = r1[0]; cvec[o] = r2[0]; }
}

__global__ void ln_stats_kernel(const float* __restrict__ x,
                                float* __restrict__ mu,
                                float* __restrict__ rstd) {
    int wave = threadIdx.x >> 6;
    int lane = threadIdx.x & 63;
    int row  = blockIdx.x * 4 + wave;  // < 12544 always (3136 blocks * 4)
    const float4* xr = reinterpret_cast<const float4*>(x + (size_t)row * D_);
    float4 v0 = xr[lane];
    float4 v1 = xr[lane + 64];
    float4 v2 = xr[lane + 128];
    float s = v0.x + v0.y + v0.z + v0.w
            + v1.x + v1.y + v1.z + v1.w
            + v2.x + v2.y + v2.z + v2.w;
    #pragma unroll
    for (int off = 32; off >= 1; off >>= 1) s += __shfl_xor(s, off);
    float m = s * (1.0f / D_);
    float q = 0.f;
    {
        float d;
        d = v0.x - m; q += d * d;  d = v0.y - m; q += d * d;
        d = v0.z - m; q += d * d;  d = v0.w - m; q += d * d;
        d = v1.x - m; q += d * d;  d = v1.y - m; q += d * d;
        d = v1.z - m; q += d * d;  d = v1.w - m; q += d * d;
        d = v2.x - m; q += d * d;  d = v2.y - m; q += d * d;
        d = v2.z - m; q += d * d;  d = v2.w - m; q += d * d;
    }
    #pragma unroll
    for (int off = 32; off >= 1; off >>= 1) q += __shfl_xor(q, off);
    if (lane == 0) {
        mu[row]   = m;
        rstd[row] = rsqrtf(q * (1.0f / D_) + 1e-5f);
    }
}

__global__ __launch_bounds__(256) void gemm_fused_kernel(
    const float* __restrict__ x,
    const float* __restrict__ ln_w,
    const float* __restrict__ ln_b,
    const float* __restrict__ Wt,
    const float* __restrict__ rowsum,
    const float* __restrict__ cvec,
    const float* __restrict__ mu,
    const float* __restrict__ rstd,
    float* __restrict__ out) {
    const int b  = blockIdx.y;
    const int nt = blockIdx.x % 12;   // d tile (12 * 64 = 768)
    const int mt = blockIdx.x / 12;   // o tile (4 * 64 = 256 >= 196)
    const int o0 = mt * 64, d0 = nt * 64;
    const int t  = threadIdx.x;
    const int tm = t >> 4, tn = t & 15;   // 16x16 thread grid, 4x4 micro-tile
    const int kk = t >> 4;                // staging row (0..15)
    const int q  = (t & 15) << 2;         // staging col*4

    __shared__ float As[16][64];  // As[kk][om] = W[o0+om][k0+kk]
    __shared__ float Xs[16][64];  // Xs[kk][dn] = xh[b][k0+kk][d0+dn]

    const float* xb  = x + (size_t)b * N_ * D_;
    const float* mub = mu + b * N_;
    const float* rsb = rstd + b * N_;

    float acc[4][4];
    #pragma unroll
    for (int i = 0; i < 4; ++i)
        #pragma unroll
        for (int j = 0; j < 4; ++j) acc[i][j] = 0.f;

    for (int k0 = 0; k0 < KPAD; k0 += 16) {
        const int krow = k0 + kk;
        float4 av = *reinterpret_cast<const float4*>(Wt + (size_t)krow * OPAD + o0 + q);
        float4 bv = make_float4(0.f, 0.f, 0.f, 0.f);
        if (krow < N_) {
            float4 xv = *reinterpret_cast<const float4*>(xb + (size_t)krow * D_ + d0 + q);
            float m_ = mub[krow], r_ = rsb[krow];
            bv.x = (xv.x - m_) * r_;
            bv.y = (xv.y - m_) * r_;
            bv.z = (xv.z - m_) * r_;
            bv.w = (xv.w - m_) * r_;
        }
        __syncthreads();
        *reinterpret_cast<float4*>(&As[kk][q]) = av;
        *reinterpret_cast<float4*>(&Xs[kk][q]) = bv;
        __syncthreads();
        #pragma unroll
        for (int kki = 0; kki < 16; ++kki) {
            float4 a4 = *reinterpret_cast<const float4*>(&As[kki][tm << 2]);
            float4 b4 = *reinterpret_cast<const float4*>(&Xs[kki][tn << 2]);
            float aa[4] = {a4.x, a4.y, a4.z, a4.w};
            float bb[4] = {b4.x, b4.y, b4.z, b4.w};
            #pragma unroll
            for (int i = 0; i < 4; ++i)
                #pragma unroll
                for (int j = 0; j < 4; ++j)
                    acc[i][j] = fmaf(aa[i], bb[j], acc[i][j]);
        }
    }

    // Epilogue: t = ln_w[d]*acc + ln_b[d]*rowsum[o] + c[o]; out = x*(gelu(t)+1)
    const int dbase = d0 + (tn << 2);
    float4 lw = *reinterpret_cast<const float4*>(ln_w + dbase);
    float4 lb = *reinterpret_cast<const float4*>(ln_b + dbase);
    float lww[4] = {lw.x, lw.y, lw.z, lw.w};
    float lbb[4] = {lb.x, lb.y, lb.z, lb.w};
    #pragma unroll
    for (int i = 0; i < 4; ++i) {
        const int o = o0 + (tm << 2) + i;
        if (o < N_) {
            const float rs = rowsum[o], cc = cvec[o];
            float4 xv = *reinterpret_cast<const float4*>(xb + (size_t)o * D_ + dbase);
            float xx[4] = {xv.x, xv.y, xv.z, xv.w};
            float4 res;
            float* rp = &res.x;
            #pragma unroll
            for (int j = 0; j < 4; ++j) {
                float T = fmaf(lww[j], acc[i][j], fmaf(lbb[j], rs, cc));
                float g = 0.5f * T * (1.0f + erff(T * 0.70710678118654752f));
                rp[j] = xx[j] * (g + 1.0f);
            }
            *reinterpret_cast<float4*>(out + ((size_t)(b * N_ + o)) * D_ + dbase) = res;
        }
    }
}

extern "C" void kernel_launch(void* const* d_in, const int* in_sizes, int n_in,
                              void* d_out, int out_size, void* d_ws, size_t ws_size,
                              hipStream_t stream) {
    const float* x    = (const float*)d_in[0];
    const float* ln_w = (const float*)d_in[1];
    const float* ln_b = (const float*)d_in[2];
    const float* sw   = (const float*)d_in[3];
    const float* sb   = (const float*)d_in[4];
    const float* dw   = (const float*)d_in[5];
    float* out = (float*)d_out;

    float* ws      = (float*)d_ws;
    float* Wt      = ws;                       // KPAD*OPAD = 53248
    float* rowsum  = Wt + KPAD * OPAD;         // 256
    float* cvec    = rowsum + OPAD;            // 256
    float* mu      = cvec + OPAD;              // 12544
    float* rstd    = mu + B_ * N_;             // 12544

    prep_w_kernel<<<OPAD, 256, 0, stream>>>(sw, sb, dw, Wt, rowsum, cvec);
    ln_stats_kernel<<<(B_ * N_) / 4, 256, 0, stream>>>(x, mu, rstd);
    gemm_fused_kernel<<<dim3(48, B_), 256, 0, stream>>>(
        x, ln_w, ln_b, Wt, rowsum, cvec, mu, rstd, out);
}